// Round 1
// baseline (530.483 us; speedup 1.0000x reference)
//
#include <hip/hip_runtime.h>
#include <math.h>

#define BB 8
#define TT 1024
#define CC 64

// ---------------------------------------------------------------------------
// Kernel 1: qkv[row, j] = bqkv[j] + sum_c x[row,c] * Wqkv[j,c]
// One 192-thread block per (b,t) row. x row staged in LDS.
// ---------------------------------------------------------------------------
__global__ __launch_bounds__(192) void qkv_kernel(const float* __restrict__ x,
                                                  const float* __restrict__ Wqkv,
                                                  const float* __restrict__ bqkv,
                                                  float* __restrict__ qkv) {
    __shared__ __align__(16) float xs[CC];
    const int row = blockIdx.x;      // 0 .. B*T-1
    const int j = threadIdx.x;       // 0 .. 191
    if (j < CC) xs[j] = x[row * CC + j];
    __syncthreads();
    const float* w = Wqkv + j * CC;
    float acc = bqkv[j];
    #pragma unroll
    for (int c = 0; c < CC; c += 4) {
        float4 wq = *(const float4*)(w + c);
        float4 xq = *(const float4*)(xs + c);
        acc += wq.x * xq.x + wq.y * xq.y + wq.z * xq.z + wq.w * xq.w;
    }
    qkv[row * 192 + j] = acc;
}

// ---------------------------------------------------------------------------
// Kernel 2: one 256-thread block per (b,t) row.
//   scores[s] = (q·k[b,s] + q·embk[t-s]) / sqrt(C)   for s<=t
//   softmax over s, then
//   y[c] = sum_s p[s] * (v[b,s,c] + embv[t-s,c])
//   out[b,t,j] = bproj[j] + sum_c y[c] * Wproj[j,c]
// ---------------------------------------------------------------------------
__global__ __launch_bounds__(256) void attn_kernel(const float* __restrict__ qkv,
                                                   const float* __restrict__ embk,
                                                   const float* __restrict__ embv,
                                                   const float* __restrict__ Wproj,
                                                   const float* __restrict__ bproj,
                                                   float* __restrict__ out) {
    __shared__ __align__(16) float qs[CC];
    __shared__ __align__(16) float sc[TT];
    __shared__ float red[256];
    __shared__ float yred[4][CC];

    const int bt = blockIdx.x;
    const int b = bt >> 10;          // / TT
    const int t = bt & (TT - 1);
    const int tid = threadIdx.x;

    // stage q row into LDS
    if (tid < CC) qs[tid] = qkv[bt * 192 + tid];
    __syncthreads();

    // ---- Stage A: scores for s = 0..t ----
    float lmax = -1e30f;
    for (int s = tid; s <= t; s += 256) {
        const float* krow = qkv + (b * TT + s) * 192 + 64;
        const float* erow = embk + (t - s) * CC;
        float acc = 0.f;
        #pragma unroll
        for (int c = 0; c < CC; c += 4) {
            float4 kq = *(const float4*)(krow + c);
            float4 eq = *(const float4*)(erow + c);
            float4 qq = *(const float4*)(qs + c);
            acc += qq.x * (kq.x + eq.x) + qq.y * (kq.y + eq.y)
                 + qq.z * (kq.z + eq.z) + qq.w * (kq.w + eq.w);
        }
        acc *= 0.125f;               // 1/sqrt(64)
        sc[s] = acc;
        lmax = fmaxf(lmax, acc);
    }

    // ---- block max reduce ----
    red[tid] = lmax;
    __syncthreads();
    for (int off = 128; off > 0; off >>= 1) {
        if (tid < off) red[tid] = fmaxf(red[tid], red[tid + off]);
        __syncthreads();
    }
    const float m = red[0];
    __syncthreads();

    // ---- exp + sum reduce ----
    float lsum = 0.f;
    for (int s = tid; s <= t; s += 256) {
        float e = __expf(sc[s] - m);
        sc[s] = e;
        lsum += e;
    }
    red[tid] = lsum;
    __syncthreads();
    for (int off = 128; off > 0; off >>= 1) {
        if (tid < off) red[tid] += red[tid + off];
        __syncthreads();
    }
    const float inv = 1.0f / red[0];
    __syncthreads();

    // ---- Stage C: weighted value sum (content + relative) ----
    const int c = tid & 63;          // channel
    const int g = tid >> 6;          // s-group 0..3
    float acc = 0.f;
    for (int s = g; s <= t; s += 4) {
        float p = sc[s];             // LDS broadcast across the 64 lanes
        float vv = qkv[(b * TT + s) * 192 + 128 + c];   // coalesced
        float ev = embv[(t - s) * CC + c];              // coalesced
        acc += p * (vv + ev);
    }
    yred[g][c] = acc * inv;
    __syncthreads();

    // ---- fold 4 partials, reuse qs[] as y[] ----
    if (tid < CC) {
        qs[tid] = yred[0][tid] + yred[1][tid] + yred[2][tid] + yred[3][tid];
    }
    __syncthreads();

    // ---- epilogue: output projection ----
    if (tid < CC) {
        const int j = tid;
        const float* w = Wproj + j * CC;
        float o = bproj[j];
        #pragma unroll
        for (int cc = 0; cc < CC; cc += 4) {
            float4 wq = *(const float4*)(w + cc);
            float4 yq = *(const float4*)(qs + cc);
            o += wq.x * yq.x + wq.y * yq.y + wq.z * yq.z + wq.w * yq.w;
        }
        out[bt * CC + j] = o;
    }
}

extern "C" void kernel_launch(void* const* d_in, const int* in_sizes, int n_in,
                              void* d_out, int out_size, void* d_ws, size_t ws_size,
                              hipStream_t stream) {
    const float* x     = (const float*)d_in[0];
    const float* Wqkv  = (const float*)d_in[1];
    const float* bqkv  = (const float*)d_in[2];
    const float* embk  = (const float*)d_in[3];
    const float* embv  = (const float*)d_in[4];
    const float* Wproj = (const float*)d_in[5];
    const float* bproj = (const float*)d_in[6];
    float* out = (float*)d_out;
    float* qkv = (float*)d_ws;       // B*T*192 floats = 6.29 MB

    qkv_kernel<<<BB * TT, 192, 0, stream>>>(x, Wqkv, bqkv, qkv);
    attn_kernel<<<BB * TT, 256, 0, stream>>>(qkv, embk, embv, Wproj, bproj, out);
}

// Round 2
// 144.572 us; speedup vs baseline: 3.6693x; 3.6693x over previous
//
#include <hip/hip_runtime.h>
#include <math.h>

#define BB 8
#define TT 1024
#define CC 64

typedef float f32x4 __attribute__((ext_vector_type(4)));
typedef short short8 __attribute__((ext_vector_type(8)));
typedef unsigned int u32x4 __attribute__((ext_vector_type(4)));
typedef unsigned short u16;

static __device__ __forceinline__ u16 f2bf(float f) {
    union { float f; unsigned int u; } v; v.f = f;
    unsigned int r = v.u + 0x7fffu + ((v.u >> 16) & 1u);
    return (u16)(r >> 16);
}

#define MFMA16(a, b, c) __builtin_amdgcn_mfma_f32_16x16x32_bf16((a), (b), (c), 0, 0, 0)

// Workspace layout (bytes)
#define OFF_S        ((size_t)0)             // 8*1024*1024 fp32 = 33554432
#define OFF_P        ((size_t)33554432)      // 8*1024*1024 bf16 = 16777216
#define OFF_XBF      ((size_t)50331648)      // 8192*64 bf16 = 1048576
#define OFF_QBF      ((size_t)51380224)      // 1048576
#define OFF_KBF      ((size_t)52428800)      // 1048576
#define OFF_VT       ((size_t)53477376)      // 1048576  [b][c][t]
#define OFF_EKP      ((size_t)54525952)      // 1088*64 bf16 = 139264 (rows d=-32..1055)
#define OFF_EVT      ((size_t)54665216)      // 64*1088 bf16 = 139264 (cols d=-32..1055)
#define OFF_WQKV     ((size_t)54804480)      // 192*64 bf16 = 24576
#define OFF_WPROJ    ((size_t)54829056)      // 64*64 bf16 = 8192
#define WS_NEED      ((size_t)54837248)

// ---------------------------------------------------------------------------
// K0: casts + padded relative-embedding buffers (pads zeroed explicitly).
// ---------------------------------------------------------------------------
__global__ __launch_bounds__(256) void prep_kernel(const float* __restrict__ x,
                                                   const float* __restrict__ Wqkv,
                                                   const float* __restrict__ embk,
                                                   const float* __restrict__ embv,
                                                   const float* __restrict__ Wproj,
                                                   u16* __restrict__ x_bf,
                                                   u16* __restrict__ Wqkv_bf,
                                                   u16* __restrict__ embk_pad,
                                                   u16* __restrict__ embvT_pad,
                                                   u16* __restrict__ Wproj_bf) {
    const int idx = blockIdx.x * 256 + threadIdx.x;
    const int stride = gridDim.x * 256;
    for (int i = idx; i < BB * TT * CC; i += stride) x_bf[i] = f2bf(x[i]);
    for (int i = idx; i < 192 * CC; i += stride) Wqkv_bf[i] = f2bf(Wqkv[i]);
    for (int i = idx; i < CC * CC; i += stride) Wproj_bf[i] = f2bf(Wproj[i]);
    for (int i = idx; i < 1088 * CC; i += stride) {
        int r = i / CC, c = i % CC, d = r - 32;
        embk_pad[i] = (d >= 0 && d < TT) ? f2bf(embk[d * CC + c]) : (u16)0;
    }
    for (int i = idx; i < CC * 1088; i += stride) {
        int c = i / 1088, col = i % 1088, d = col - 32;
        embvT_pad[i] = (d >= 0 && d < TT) ? f2bf(embv[d * CC + c]) : (u16)0;
    }
}

// ---------------------------------------------------------------------------
// K1: qkv = x @ Wqkv^T + bqkv via MFMA. Writes q_bf, k_bf (row-major) and
// vT_bf [b][c][t] (transposed through LDS).
// Grid: (512 row-tiles, 12 o-chunks), block = 64 (1 wave).
// ---------------------------------------------------------------------------
__global__ __launch_bounds__(64) void qkv_mfma_kernel(const u16* __restrict__ x_bf,
                                                      const u16* __restrict__ Wqkv_bf,
                                                      const float* __restrict__ bqkv,
                                                      u16* __restrict__ q_bf,
                                                      u16* __restrict__ k_bf,
                                                      u16* __restrict__ vT_bf) {
    const int rt = blockIdx.x;          // row tile: rows rt*16 .. rt*16+15
    const int oc = blockIdx.y;          // output 16-col chunk 0..11
    const int lane = threadIdx.x, quad = lane >> 4, l15 = lane & 15;
    const int row0 = rt * 16;

    const u16* xrow = x_bf + (size_t)(row0 + l15) * CC;
    short8 a0 = *(const short8*)(xrow + quad * 8);
    short8 a1 = *(const short8*)(xrow + 32 + quad * 8);
    const u16* wrow = Wqkv_bf + (size_t)(oc * 16 + l15) * CC;
    short8 b0 = *(const short8*)(wrow + quad * 8);
    short8 b1 = *(const short8*)(wrow + 32 + quad * 8);
    f32x4 acc = {0.f, 0.f, 0.f, 0.f};
    acc = MFMA16(a0, b0, acc);
    acc = MFMA16(a1, b1, acc);
    const float bias = bqkv[oc * 16 + l15];   // col = oc*16 + l15 for all 4 regs

    if (oc < 8) {
        u16* dst = (oc < 4) ? q_bf : k_bf;
        const int c = (oc & 3) * 16 + l15;
        #pragma unroll
        for (int r = 0; r < 4; ++r)
            dst[(size_t)(row0 + quad * 4 + r) * CC + c] = f2bf(acc[r] + bias);
    } else {
        __shared__ float vt[16][17];
        #pragma unroll
        for (int r = 0; r < 4; ++r) vt[quad * 4 + r][l15] = acc[r] + bias;
        __syncthreads();
        const int c_l = lane >> 2;              // 0..15
        const int tbase = (lane & 3) * 4;       // 0,4,8,12
        const int b = row0 >> 10, t0 = row0 & (TT - 1);
        u16 p[4];
        #pragma unroll
        for (int tt2 = 0; tt2 < 4; ++tt2) p[tt2] = f2bf(vt[tbase + tt2][c_l]);
        unsigned long long pk = (unsigned long long)p[0] | ((unsigned long long)p[1] << 16)
                              | ((unsigned long long)p[2] << 32) | ((unsigned long long)p[3] << 48);
        *(unsigned long long*)&vT_bf[(size_t)(b * CC + (oc - 8) * 16 + c_l) * TT + t0 + tbase] = pk;
    }
}

// ---------------------------------------------------------------------------
// K2: S[t,s] = (q·k + q·embk[t-s]) * 0.125, causal-masked, fp32 to global.
// Relative term via banded MFMA: Rband[i,u] = q[t0+i]·embk[dbase+u], u=31+i-j.
// Grid: (32 s-tiles, 64 t-tiles, 8 b), block = 64 (1 wave), 16x32 tile.
// ---------------------------------------------------------------------------
__global__ __launch_bounds__(64) void scores_kernel(const u16* __restrict__ q_bf,
                                                    const u16* __restrict__ k_bf,
                                                    const u16* __restrict__ embk_pad,
                                                    float* __restrict__ S) {
    const int st = blockIdx.x, tt = blockIdx.y, b = blockIdx.z;
    const int t0 = tt * 16, s0 = st * 32;
    if (s0 > t0 + 15) return;
    const int lane = threadIdx.x, quad = lane >> 4, l15 = lane & 15;

    const u16* qrow = q_bf + (size_t)((b << 10) + t0 + l15) * CC;
    short8 aq0 = *(const short8*)(qrow + quad * 8);
    short8 aq1 = *(const short8*)(qrow + 32 + quad * 8);

    f32x4 cfr[2];
    #pragma unroll
    for (int cb = 0; cb < 2; ++cb) {
        const u16* krow = k_bf + (size_t)((b << 10) + s0 + cb * 16 + l15) * CC;
        short8 b0 = *(const short8*)(krow + quad * 8);
        short8 b1 = *(const short8*)(krow + 32 + quad * 8);
        f32x4 acc = {0.f, 0.f, 0.f, 0.f};
        acc = MFMA16(aq0, b0, acc);
        acc = MFMA16(aq1, b1, acc);
        cfr[cb] = acc;
    }

    const int dbase = t0 - s0 - 31;
    __shared__ float rband[16 * 48];
    #pragma unroll
    for (int nb = 0; nb < 3; ++nb) {
        const u16* erow = embk_pad + (size_t)(dbase + 32 + nb * 16 + l15) * CC;
        short8 b0 = *(const short8*)(erow + quad * 8);
        short8 b1 = *(const short8*)(erow + 32 + quad * 8);
        f32x4 acc = {0.f, 0.f, 0.f, 0.f};
        acc = MFMA16(aq0, b0, acc);
        acc = MFMA16(aq1, b1, acc);
        #pragma unroll
        for (int r = 0; r < 4; ++r) rband[(quad * 4 + r) * 48 + nb * 16 + l15] = acc[r];
    }
    __syncthreads();

    #pragma unroll
    for (int cb = 0; cb < 2; ++cb)
        #pragma unroll
        for (int r = 0; r < 4; ++r) {
            const int i = quad * 4 + r, j = cb * 16 + l15;
            const int d = t0 - s0 + i - j;
            float val = -1e30f;
            if (d >= 0) val = (cfr[cb][r] + rband[i * 48 + (31 + i - j)]) * 0.125f;
            S[((size_t)((b << 10) + t0 + i) << 10) + s0 + j] = val;
        }
}

// ---------------------------------------------------------------------------
// K3: row softmax over s<=t; writes P bf16 (zeros for s>t).
// ---------------------------------------------------------------------------
__global__ __launch_bounds__(256) void softmax_kernel(const float* __restrict__ S,
                                                      u16* __restrict__ P_bf) {
    const int row = blockIdx.x;
    const int t = row & (TT - 1);
    const float* srow = S + ((size_t)row << 10);
    u16* prow = P_bf + ((size_t)row << 10);
    const int tid = threadIdx.x;
    __shared__ float red[256];

    float lmax = -1e30f;
    for (int s = tid; s <= t; s += 256) lmax = fmaxf(lmax, srow[s]);
    red[tid] = lmax; __syncthreads();
    for (int off = 128; off; off >>= 1) { if (tid < off) red[tid] = fmaxf(red[tid], red[tid + off]); __syncthreads(); }
    const float m = red[0]; __syncthreads();

    float lsum = 0.f;
    for (int s = tid; s <= t; s += 256) lsum += __expf(srow[s] - m);
    red[tid] = lsum; __syncthreads();
    for (int off = 128; off; off >>= 1) { if (tid < off) red[tid] += red[tid + off]; __syncthreads(); }
    const float inv = 1.0f / red[0];

    for (int s = tid; s < TT; s += 256)
        prow[s] = (s <= t) ? f2bf(__expf(srow[s] - m) * inv) : (u16)0;
}

// ---------------------------------------------------------------------------
// K4: y = P@V + skew(P)@embv, then out = y@Wproj^T + bproj.
// Block = 256 (4 waves); each wave owns one 16-row t-tile's s-tiles st=w,w+4,...
// y2 via per-wave LDS skew-scatter of P into A-layout (u = 32+i-j, 16B-aligned
// embvT reads since t0,s0 are multiples of 16).
// Grid: (64 t-tiles descending, 8 b).
// ---------------------------------------------------------------------------
__global__ __launch_bounds__(256) void out_kernel(const u16* __restrict__ P_bf,
                                                  const u16* __restrict__ vT_bf,
                                                  const u16* __restrict__ embvT_pad,
                                                  const u16* __restrict__ Wproj_bf,
                                                  const float* __restrict__ bproj,
                                                  float* __restrict__ out) {
    const int b = blockIdx.y;
    const int t0 = 1008 - (int)blockIdx.x * 16;   // big tiles dispatch first
    const int tid = threadIdx.x;
    const int w = tid >> 6, lane = tid & 63, quad = lane >> 4, l15 = lane & 15;

    __shared__ __align__(16) u16 a2buf[4][16 * 64];
    __shared__ float ypart[4][16][64];
    __shared__ __align__(16) u16 yA[16 * 64];

    f32x4 acc[4];
    #pragma unroll
    for (int nb = 0; nb < 4; ++nb) acc[nb] = (f32x4){0.f, 0.f, 0.f, 0.f};

    const int nst = (t0 + 15) / 32 + 1;
    u16* a2 = a2buf[w];

    for (int st = w; st < nst; st += 4) {
        const int s0 = st * 32;
        // P A-fragment: A[m=l15][k=quad*8+jj] = P[t0+l15][s0+k]
        const u16* prow = P_bf + (((size_t)((b << 10) + t0 + l15)) << 10) + s0;
        short8 aP = *(const short8*)(prow + quad * 8);

        // y1 += P @ V   (B from vT: lane n = channel, k contiguous in t)
        #pragma unroll
        for (int nb = 0; nb < 4; ++nb) {
            const u16* vrow = vT_bf + ((size_t)(b * CC + nb * 16 + l15) << 10) + s0;
            short8 bv = *(const short8*)(vrow + quad * 8);
            acc[nb] = MFMA16(aP, bv, acc[nb]);
        }

        // y2: zero A2 (16x64 bf16), skew-scatter P: A2[i][u=32+i-j] = P[i][j]
        u32x4 z = {0u, 0u, 0u, 0u};
        ((u32x4*)a2)[lane * 2] = z;
        ((u32x4*)a2)[lane * 2 + 1] = z;
        #pragma unroll
        for (int jj = 0; jj < 8; ++jj) {
            const int i = l15, j = quad * 8 + jj;
            a2[i * 64 + (32 + i - j)] = (u16)aP[jj];
        }
        asm volatile("s_waitcnt lgkmcnt(0)" ::: "memory");

        // y2 += A2 @ embv_band ; embvT col base = (t0-s0), 16B aligned
        const int dcol0 = t0 - s0;
        #pragma unroll
        for (int kk = 0; kk < 2; ++kk) {
            short8 a2f = *(const short8*)(a2 + l15 * 64 + kk * 32 + quad * 8);
            #pragma unroll
            for (int nb = 0; nb < 4; ++nb) {
                const u16* erow = embvT_pad + (size_t)(nb * 16 + l15) * 1088 + dcol0 + kk * 32 + quad * 8;
                short8 be = *(const short8*)erow;
                acc[nb] = MFMA16(a2f, be, acc[nb]);
            }
        }
    }

    // combine wave partials
    #pragma unroll
    for (int nb = 0; nb < 4; ++nb)
        #pragma unroll
        for (int r = 0; r < 4; ++r)
            ypart[w][quad * 4 + r][nb * 16 + l15] = acc[nb][r];
    __syncthreads();
    for (int e = tid; e < 16 * 64; e += 256) {
        const int i = e >> 6, c = e & 63;
        yA[e] = f2bf(ypart[0][i][c] + ypart[1][i][c] + ypart[2][i][c] + ypart[3][i][c]);
    }
    __syncthreads();

    // proj: wave w computes output cols w*16 .. w*16+15
    short8 a0 = *(const short8*)(yA + l15 * 64 + quad * 8);
    short8 a1 = *(const short8*)(yA + l15 * 64 + 32 + quad * 8);
    const u16* wrow = Wproj_bf + (size_t)(w * 16 + l15) * CC;
    short8 b0 = *(const short8*)(wrow + quad * 8);
    short8 b1 = *(const short8*)(wrow + 32 + quad * 8);
    f32x4 o = {0.f, 0.f, 0.f, 0.f};
    o = MFMA16(a0, b0, o);
    o = MFMA16(a1, b1, o);
    const float bias = bproj[w * 16 + l15];
    #pragma unroll
    for (int r = 0; r < 4; ++r)
        out[(size_t)((b << 10) + t0 + quad * 4 + r) * CC + w * 16 + l15] = o[r] + bias;
}

// ===========================================================================
// Fallback path (round-1 verified fp32 kernels) — used if ws_size < WS_NEED.
// ===========================================================================
__global__ __launch_bounds__(192) void qkv_kernel(const float* __restrict__ x,
                                                  const float* __restrict__ Wqkv,
                                                  const float* __restrict__ bqkv,
                                                  float* __restrict__ qkv) {
    __shared__ __align__(16) float xs[CC];
    const int row = blockIdx.x;
    const int j = threadIdx.x;
    if (j < CC) xs[j] = x[row * CC + j];
    __syncthreads();
    const float* w = Wqkv + j * CC;
    float acc = bqkv[j];
    #pragma unroll
    for (int c = 0; c < CC; c += 4) {
        float4 wq = *(const float4*)(w + c);
        float4 xq = *(const float4*)(xs + c);
        acc += wq.x * xq.x + wq.y * xq.y + wq.z * xq.z + wq.w * xq.w;
    }
    qkv[row * 192 + j] = acc;
}

__global__ __launch_bounds__(256) void attn_kernel(const float* __restrict__ qkv,
                                                   const float* __restrict__ embk,
                                                   const float* __restrict__ embv,
                                                   const float* __restrict__ Wproj,
                                                   const float* __restrict__ bproj,
                                                   float* __restrict__ out) {
    __shared__ __align__(16) float qs[CC];
    __shared__ __align__(16) float sc[TT];
    __shared__ float red[256];
    __shared__ float yred[4][CC];
    const int bt = blockIdx.x;
    const int b = bt >> 10, t = bt & (TT - 1);
    const int tid = threadIdx.x;
    if (tid < CC) qs[tid] = qkv[bt * 192 + tid];
    __syncthreads();
    float lmax = -1e30f;
    for (int s = tid; s <= t; s += 256) {
        const float* krow = qkv + (b * TT + s) * 192 + 64;
        const float* erow = embk + (t - s) * CC;
        float acc = 0.f;
        #pragma unroll
        for (int c = 0; c < CC; c += 4) {
            float4 kq = *(const float4*)(krow + c);
            float4 eq = *(const float4*)(erow + c);
            float4 qq = *(const float4*)(qs + c);
            acc += qq.x * (kq.x + eq.x) + qq.y * (kq.y + eq.y)
                 + qq.z * (kq.z + eq.z) + qq.w * (kq.w + eq.w);
        }
        acc *= 0.125f;
        sc[s] = acc;
        lmax = fmaxf(lmax, acc);
    }
    red[tid] = lmax; __syncthreads();
    for (int off = 128; off > 0; off >>= 1) { if (tid < off) red[tid] = fmaxf(red[tid], red[tid + off]); __syncthreads(); }
    const float m = red[0]; __syncthreads();
    float lsum = 0.f;
    for (int s = tid; s <= t; s += 256) { float e = __expf(sc[s] - m); sc[s] = e; lsum += e; }
    red[tid] = lsum; __syncthreads();
    for (int off = 128; off > 0; off >>= 1) { if (tid < off) red[tid] += red[tid + off]; __syncthreads(); }
    const float inv = 1.0f / red[0]; __syncthreads();
    const int c = tid & 63, g = tid >> 6;
    float acc = 0.f;
    for (int s = g; s <= t; s += 4) {
        float p = sc[s];
        float vv = qkv[(b * TT + s) * 192 + 128 + c];
        float ev = embv[(t - s) * CC + c];
        acc += p * (vv + ev);
    }
    yred[g][c] = acc * inv;
    __syncthreads();
    if (tid < CC) qs[tid] = yred[0][tid] + yred[1][tid] + yred[2][tid] + yred[3][tid];
    __syncthreads();
    if (tid < CC) {
        const float* w = Wproj + tid * CC;
        float o = bproj[tid];
        #pragma unroll
        for (int cc2 = 0; cc2 < CC; cc2 += 4) {
            float4 wq = *(const float4*)(w + cc2);
            float4 yq = *(const float4*)(qs + cc2);
            o += wq.x * yq.x + wq.y * yq.y + wq.z * yq.z + wq.w * yq.w;
        }
        out[bt * CC + tid] = o;
    }
}

extern "C" void kernel_launch(void* const* d_in, const int* in_sizes, int n_in,
                              void* d_out, int out_size, void* d_ws, size_t ws_size,
                              hipStream_t stream) {
    const float* x     = (const float*)d_in[0];
    const float* Wqkv  = (const float*)d_in[1];
    const float* bqkv  = (const float*)d_in[2];
    const float* embk  = (const float*)d_in[3];
    const float* embv  = (const float*)d_in[4];
    const float* Wproj = (const float*)d_in[5];
    const float* bproj = (const float*)d_in[6];
    float* out = (float*)d_out;

    if (ws_size < WS_NEED) {
        // Fallback: round-1 verified fp32 path (needs 6.3 MB)
        float* qkv = (float*)d_ws;
        qkv_kernel<<<BB * TT, 192, 0, stream>>>(x, Wqkv, bqkv, qkv);
        attn_kernel<<<BB * TT, 256, 0, stream>>>(qkv, embk, embv, Wproj, bproj, out);
        return;
    }

    char* ws = (char*)d_ws;
    float* S        = (float*)(ws + OFF_S);
    u16* P_bf       = (u16*)(ws + OFF_P);
    u16* x_bf       = (u16*)(ws + OFF_XBF);
    u16* q_bf       = (u16*)(ws + OFF_QBF);
    u16* k_bf       = (u16*)(ws + OFF_KBF);
    u16* vT_bf      = (u16*)(ws + OFF_VT);
    u16* embk_pad   = (u16*)(ws + OFF_EKP);
    u16* embvT_pad  = (u16*)(ws + OFF_EVT);
    u16* Wqkv_bf    = (u16*)(ws + OFF_WQKV);
    u16* Wproj_bf   = (u16*)(ws + OFF_WPROJ);

    prep_kernel<<<512, 256, 0, stream>>>(x, Wqkv, embk, embv, Wproj,
                                         x_bf, Wqkv_bf, embk_pad, embvT_pad, Wproj_bf);
    qkv_mfma_kernel<<<dim3(512, 12), 64, 0, stream>>>(x_bf, Wqkv_bf, bqkv, q_bf, k_bf, vT_bf);
    scores_kernel<<<dim3(32, 64, 8), 64, 0, stream>>>(q_bf, k_bf, embk_pad, S);
    softmax_kernel<<<BB * TT, 256, 0, stream>>>(S, P_bf);
    out_kernel<<<dim3(64, 8), 256, 0, stream>>>(P_bf, vT_bf, embvT_pad, Wproj_bf, bproj, out);
}

// Round 3
// 121.806 us; speedup vs baseline: 4.3551x; 1.1869x over previous
//
#include <hip/hip_runtime.h>
#include <math.h>

#define BB 8
#define TT 1024
#define CC 64

typedef float f32x4 __attribute__((ext_vector_type(4)));
typedef short short8 __attribute__((ext_vector_type(8)));
typedef unsigned int u32x4 __attribute__((ext_vector_type(4)));
typedef unsigned short u16;

static __device__ __forceinline__ u16 f2bf(float f) {
    union { float f; unsigned int u; } v; v.f = f;
    unsigned int r = v.u + 0x7fffu + ((v.u >> 16) & 1u);
    return (u16)(r >> 16);
}
static __device__ __forceinline__ float bf2f(u16 h) {
    union { unsigned int u; float f; } v; v.u = ((unsigned int)h) << 16; return v.f;
}

#define MFMA16(a, b, c) __builtin_amdgcn_mfma_f32_16x16x32_bf16((a), (b), (c), 0, 0, 0)

// Workspace layout (bytes) — no S / P anymore
#define OFF_XBF      ((size_t)0)             // 8192*64 bf16 = 1048576
#define OFF_QBF      ((size_t)1048576)
#define OFF_KBF      ((size_t)2097152)
#define OFF_VT       ((size_t)3145728)       // [b][c][t]
#define OFF_EKP      ((size_t)4194304)       // 1088*64 bf16 (rows d=-32..1055)
#define OFF_EVT      ((size_t)4333568)       // 64*1088 bf16 (cols d=-32..1055)
#define OFF_WQKV     ((size_t)4472832)       // 192*64 bf16
#define OFF_WPROJ    ((size_t)4497408)       // 64*64 bf16
#define WS_NEED      ((size_t)4505600)

// ---------------------------------------------------------------------------
// K0: casts + padded relative-embedding buffers.
// ---------------------------------------------------------------------------
__global__ __launch_bounds__(256) void prep_kernel(const float* __restrict__ x,
                                                   const float* __restrict__ Wqkv,
                                                   const float* __restrict__ embk,
                                                   const float* __restrict__ embv,
                                                   const float* __restrict__ Wproj,
                                                   u16* __restrict__ x_bf,
                                                   u16* __restrict__ Wqkv_bf,
                                                   u16* __restrict__ embk_pad,
                                                   u16* __restrict__ embvT_pad,
                                                   u16* __restrict__ Wproj_bf) {
    const int idx = blockIdx.x * 256 + threadIdx.x;
    const int stride = gridDim.x * 256;
    for (int i = idx; i < BB * TT * CC; i += stride) x_bf[i] = f2bf(x[i]);
    for (int i = idx; i < 192 * CC; i += stride) Wqkv_bf[i] = f2bf(Wqkv[i]);
    for (int i = idx; i < CC * CC; i += stride) Wproj_bf[i] = f2bf(Wproj[i]);
    for (int i = idx; i < 1088 * CC; i += stride) {
        int r = i / CC, c = i % CC, d = r - 32;
        embk_pad[i] = (d >= 0 && d < TT) ? f2bf(embk[d * CC + c]) : (u16)0;
    }
    for (int i = idx; i < CC * 1088; i += stride) {
        int c = i / 1088, col = i % 1088, d = col - 32;
        embvT_pad[i] = (d >= 0 && d < TT) ? f2bf(embv[d * CC + c]) : (u16)0;
    }
}

// ---------------------------------------------------------------------------
// K1: qkv = x @ Wqkv^T + bqkv via MFMA (verified R2). q/k row-major bf16,
// v transposed to [b][c][t] through LDS.
// ---------------------------------------------------------------------------
__global__ __launch_bounds__(64) void qkv_mfma_kernel(const u16* __restrict__ x_bf,
                                                      const u16* __restrict__ Wqkv_bf,
                                                      const float* __restrict__ bqkv,
                                                      u16* __restrict__ q_bf,
                                                      u16* __restrict__ k_bf,
                                                      u16* __restrict__ vT_bf) {
    const int rt = blockIdx.x;
    const int oc = blockIdx.y;          // output 16-col chunk 0..11
    const int lane = threadIdx.x, quad = lane >> 4, l15 = lane & 15;
    const int row0 = rt * 16;

    const u16* xrow = x_bf + (size_t)(row0 + l15) * CC;
    short8 a0 = *(const short8*)(xrow + quad * 8);
    short8 a1 = *(const short8*)(xrow + 32 + quad * 8);
    const u16* wrow = Wqkv_bf + (size_t)(oc * 16 + l15) * CC;
    short8 b0 = *(const short8*)(wrow + quad * 8);
    short8 b1 = *(const short8*)(wrow + 32 + quad * 8);
    f32x4 acc = {0.f, 0.f, 0.f, 0.f};
    acc = MFMA16(a0, b0, acc);
    acc = MFMA16(a1, b1, acc);
    const float bias = bqkv[oc * 16 + l15];

    if (oc < 8) {
        u16* dst = (oc < 4) ? q_bf : k_bf;
        const int c = (oc & 3) * 16 + l15;
        #pragma unroll
        for (int r = 0; r < 4; ++r)
            dst[(size_t)(row0 + quad * 4 + r) * CC + c] = f2bf(acc[r] + bias);
    } else {
        __shared__ float vt[16][17];
        #pragma unroll
        for (int r = 0; r < 4; ++r) vt[quad * 4 + r][l15] = acc[r] + bias;
        __syncthreads();
        const int c_l = lane >> 2;
        const int tbase = (lane & 3) * 4;
        const int b = row0 >> 10, t0 = row0 & (TT - 1);
        u16 p[4];
        #pragma unroll
        for (int tt2 = 0; tt2 < 4; ++tt2) p[tt2] = f2bf(vt[tbase + tt2][c_l]);
        unsigned long long pk = (unsigned long long)p[0] | ((unsigned long long)p[1] << 16)
                              | ((unsigned long long)p[2] << 32) | ((unsigned long long)p[3] << 48);
        *(unsigned long long*)&vT_bf[(size_t)(b * CC + (oc - 8) * 16 + c_l) * TT + t0 + tbase] = pk;
    }
}

// ---------------------------------------------------------------------------
// K2 (fused flash-style): scores (content MFMA + relative-band MFMA) ->
// online softmax (per-row m,l in regs, butterfly reductions) ->
// y1 = P@V, y2 = skew(P)@embv accumulated unnormalized in AGPRs ->
// wave-partial merge in LDS -> Wproj MFMA epilogue.
// Block = 256 (4 waves); wave w handles s-tiles st = w, w+4, ...
// Grid: (64 t-tiles, descending t0), 8 b.
// ---------------------------------------------------------------------------
__global__ __launch_bounds__(256) void fused_attn_kernel(const u16* __restrict__ q_bf,
                                                         const u16* __restrict__ k_bf,
                                                         const u16* __restrict__ vT_bf,
                                                         const u16* __restrict__ embk_pad,
                                                         const u16* __restrict__ embvT_pad,
                                                         const u16* __restrict__ Wproj_bf,
                                                         const float* __restrict__ bproj,
                                                         float* __restrict__ out) {
    const int b = blockIdx.y;
    const int t0 = 1008 - (int)blockIdx.x * 16;   // big tiles dispatch first
    const int tid = threadIdx.x;
    const int w = tid >> 6, lane = tid & 63, quad = lane >> 4, l15 = lane & 15;

    __shared__ __align__(16) u16 a2buf[4][16 * 72];   // skewed P, pad 64->72 (bank spread)
    __shared__ __align__(16) u16 pbuf[4][16 * 40];    // P row-major, pad 32->40
    __shared__ float rbandbuf[4][16 * 49];            // rel band, pad 48->49
    __shared__ float ypart[4][16][64];
    __shared__ float mpart[4][16], lpart[4][16];
    __shared__ __align__(16) u16 yA[16 * 64];

    u16* a2 = a2buf[w];
    u16* pt = pbuf[w];
    float* rband = rbandbuf[w];

    // hoisted Q fragments (constant over the s-loop)
    const u16* qrow = q_bf + (size_t)((b << 10) + t0 + l15) * CC;
    short8 aq0 = *(const short8*)(qrow + quad * 8);
    short8 aq1 = *(const short8*)(qrow + 32 + quad * 8);

    f32x4 acc[4];
    #pragma unroll
    for (int nb = 0; nb < 4; ++nb) acc[nb] = (f32x4){0.f, 0.f, 0.f, 0.f};
    float m_old[4] = {-1e30f, -1e30f, -1e30f, -1e30f};
    float l_run[4] = {0.f, 0.f, 0.f, 0.f};

    const int nst = (t0 >> 5) + 1;

    for (int st = w; st < nst; st += 4) {
        const int s0 = st * 32;

        // ---- content scores: 16x32 tile, 2 column blocks ----
        f32x4 sc[2];
        #pragma unroll
        for (int cb = 0; cb < 2; ++cb) {
            const u16* krow = k_bf + (size_t)((b << 10) + s0 + cb * 16 + l15) * CC;
            short8 kb0 = *(const short8*)(krow + quad * 8);
            short8 kb1 = *(const short8*)(krow + 32 + quad * 8);
            f32x4 a = {0.f, 0.f, 0.f, 0.f};
            a = MFMA16(aq0, kb0, a);
            a = MFMA16(aq1, kb1, a);
            sc[cb] = a;
        }

        // ---- relative band: Rband[i,u] = q[t0+i]·embk[dbase+u], u=31+i-j ----
        const int dbase = t0 - s0 - 31;
        #pragma unroll
        for (int nb = 0; nb < 3; ++nb) {
            const u16* erow = embk_pad + (size_t)(dbase + 32 + nb * 16 + l15) * CC;
            short8 eb0 = *(const short8*)(erow + quad * 8);
            short8 eb1 = *(const short8*)(erow + 32 + quad * 8);
            f32x4 a = {0.f, 0.f, 0.f, 0.f};
            a = MFMA16(aq0, eb0, a);
            a = MFMA16(aq1, eb1, a);
            #pragma unroll
            for (int r = 0; r < 4; ++r) rband[(quad * 4 + r) * 49 + nb * 16 + l15] = a[r];
        }
        asm volatile("s_waitcnt lgkmcnt(0)" ::: "memory");

        // ---- assemble masked scores ----
        float sv[2][4];
        #pragma unroll
        for (int cb = 0; cb < 2; ++cb)
            #pragma unroll
            for (int r = 0; r < 4; ++r) {
                const int i = quad * 4 + r, j = cb * 16 + l15;
                const int d = t0 - s0 + i - j;
                sv[cb][r] = (d >= 0) ? (sc[cb][r] + rband[i * 49 + (31 + i - j)]) * 0.125f
                                     : -1e30f;
            }

        // ---- online softmax: row max (butterfly over 16-lane col group) ----
        float tmax[4];
        #pragma unroll
        for (int r = 0; r < 4; ++r) tmax[r] = fmaxf(sv[0][r], sv[1][r]);
        #pragma unroll
        for (int msk = 1; msk < 16; msk <<= 1)
            #pragma unroll
            for (int r = 0; r < 4; ++r) tmax[r] = fmaxf(tmax[r], __shfl_xor(tmax[r], msk, 64));

        float m_new[4], scale[4];
        #pragma unroll
        for (int r = 0; r < 4; ++r) {
            m_new[r] = fmaxf(m_old[r], tmax[r]);
            scale[r] = __expf(m_old[r] - m_new[r]);
        }

        // p (bf16-rounded, used for BOTH numerator MFMA and denominator sum)
        float p0[4], p1[4], rsum[4];
        u16 pb0[4], pb1[4];
        #pragma unroll
        for (int r = 0; r < 4; ++r) {
            pb0[r] = f2bf(__expf(sv[0][r] - m_new[r]));
            pb1[r] = f2bf(__expf(sv[1][r] - m_new[r]));
            p0[r] = bf2f(pb0[r]);
            p1[r] = bf2f(pb1[r]);
            rsum[r] = p0[r] + p1[r];
        }
        #pragma unroll
        for (int msk = 1; msk < 16; msk <<= 1)
            #pragma unroll
            for (int r = 0; r < 4; ++r) rsum[r] += __shfl_xor(rsum[r], msk, 64);

        #pragma unroll
        for (int r = 0; r < 4; ++r) {
            l_run[r] = l_run[r] * scale[r] + rsum[r];
            m_old[r] = m_new[r];
        }
        #pragma unroll
        for (int nb = 0; nb < 4; ++nb)
            #pragma unroll
            for (int r = 0; r < 4; ++r) acc[nb][r] *= scale[r];

        // ---- write P to LDS: row-major (pt) and skewed (a2) ----
        u32x4 z = {0u, 0u, 0u, 0u};
        #pragma unroll
        for (int e = 0; e < 3; ++e) {          // 144 u32x4 = 16*72 u16
            int idx = lane + e * 64;
            if (idx < 144) ((u32x4*)a2)[idx] = z;
        }
        #pragma unroll
        for (int r = 0; r < 4; ++r) {
            const int i = quad * 4 + r;
            pt[i * 40 + l15] = pb0[r];
            pt[i * 40 + 16 + l15] = pb1[r];
            a2[i * 72 + (32 + i - l15)] = pb0[r];          // j = l15
            a2[i * 72 + (16 + i - l15)] = pb1[r];          // j = 16+l15 -> 32+i-j
        }
        asm volatile("s_waitcnt lgkmcnt(0)" ::: "memory");

        // ---- y1 += P @ V ----
        short8 aP = *(const short8*)(pt + l15 * 40 + quad * 8);
        #pragma unroll
        for (int nb = 0; nb < 4; ++nb) {
            const u16* vrow = vT_bf + ((size_t)(b * CC + nb * 16 + l15) << 10) + s0;
            short8 bv = *(const short8*)(vrow + quad * 8);
            acc[nb] = MFMA16(aP, bv, acc[nb]);
        }

        // ---- y2 += skew(P) @ embv band ----
        const int dcol0 = t0 - s0;
        #pragma unroll
        for (int kk = 0; kk < 2; ++kk) {
            short8 a2f = *(const short8*)(a2 + l15 * 72 + kk * 32 + quad * 8);
            #pragma unroll
            for (int nb = 0; nb < 4; ++nb) {
                const u16* erow = embvT_pad + (size_t)(nb * 16 + l15) * 1088 + dcol0 + kk * 32 + quad * 8;
                short8 be = *(const short8*)erow;
                acc[nb] = MFMA16(a2f, be, acc[nb]);
            }
        }
    }

    // ---- store wave partials ----
    #pragma unroll
    for (int nb = 0; nb < 4; ++nb)
        #pragma unroll
        for (int r = 0; r < 4; ++r)
            ypart[w][quad * 4 + r][nb * 16 + l15] = acc[nb][r];
    if (l15 == 0) {
        #pragma unroll
        for (int r = 0; r < 4; ++r) {
            mpart[w][quad * 4 + r] = m_old[r];
            lpart[w][quad * 4 + r] = l_run[r];
        }
    }
    __syncthreads();

    // ---- merge 4 online-softmax states, normalize, cast to bf16 ----
    for (int e = tid; e < 16 * 64; e += 256) {
        const int i = e >> 6, c = e & 63;
        float M = fmaxf(fmaxf(mpart[0][i], mpart[1][i]), fmaxf(mpart[2][i], mpart[3][i]));
        float Y = 0.f, L = 0.f;
        #pragma unroll
        for (int w2 = 0; w2 < 4; ++w2) {
            float f = __expf(mpart[w2][i] - M);
            Y += ypart[w2][i][c] * f;
            L += lpart[w2][i] * f;
        }
        yA[e] = f2bf(Y / L);
    }
    __syncthreads();

    // ---- epilogue: out = y @ Wproj^T + bproj (wave w -> cols w*16..+15) ----
    short8 a0 = *(const short8*)(yA + l15 * 64 + quad * 8);
    short8 a1 = *(const short8*)(yA + l15 * 64 + 32 + quad * 8);
    const u16* wrow = Wproj_bf + (size_t)(w * 16 + l15) * CC;
    short8 wb0 = *(const short8*)(wrow + quad * 8);
    short8 wb1 = *(const short8*)(wrow + 32 + quad * 8);
    f32x4 o = {0.f, 0.f, 0.f, 0.f};
    o = MFMA16(a0, wb0, o);
    o = MFMA16(a1, wb1, o);
    const float bias = bproj[w * 16 + l15];
    #pragma unroll
    for (int r = 0; r < 4; ++r)
        out[(size_t)((b << 10) + t0 + quad * 4 + r) * CC + w * 16 + l15] = o[r] + bias;
}

// ===========================================================================
// Fallback path (round-1 verified fp32 kernels) — used if ws_size < WS_NEED.
// ===========================================================================
__global__ __launch_bounds__(192) void qkv_kernel(const float* __restrict__ x,
                                                  const float* __restrict__ Wqkv,
                                                  const float* __restrict__ bqkv,
                                                  float* __restrict__ qkv) {
    __shared__ __align__(16) float xs[CC];
    const int row = blockIdx.x;
    const int j = threadIdx.x;
    if (j < CC) xs[j] = x[row * CC + j];
    __syncthreads();
    const float* w = Wqkv + j * CC;
    float acc = bqkv[j];
    #pragma unroll
    for (int c = 0; c < CC; c += 4) {
        float4 wq = *(const float4*)(w + c);
        float4 xq = *(const float4*)(xs + c);
        acc += wq.x * xq.x + wq.y * xq.y + wq.z * xq.z + wq.w * xq.w;
    }
    qkv[row * 192 + j] = acc;
}

__global__ __launch_bounds__(256) void attn_kernel(const float* __restrict__ qkv,
                                                   const float* __restrict__ embk,
                                                   const float* __restrict__ embv,
                                                   const float* __restrict__ Wproj,
                                                   const float* __restrict__ bproj,
                                                   float* __restrict__ out) {
    __shared__ __align__(16) float qs[CC];
    __shared__ __align__(16) float sc[TT];
    __shared__ float red[256];
    __shared__ float yred[4][CC];
    const int bt = blockIdx.x;
    const int b = bt >> 10, t = bt & (TT - 1);
    const int tid = threadIdx.x;
    if (tid < CC) qs[tid] = qkv[bt * 192 + tid];
    __syncthreads();
    float lmax = -1e30f;
    for (int s = tid; s <= t; s += 256) {
        const float* krow = qkv + (b * TT + s) * 192 + 64;
        const float* erow = embk + (t - s) * CC;
        float acc = 0.f;
        #pragma unroll
        for (int c = 0; c < CC; c += 4) {
            float4 kq = *(const float4*)(krow + c);
            float4 eq = *(const float4*)(erow + c);
            float4 qq = *(const float4*)(qs + c);
            acc += qq.x * (kq.x + eq.x) + qq.y * (kq.y + eq.y)
                 + qq.z * (kq.z + eq.z) + qq.w * (kq.w + eq.w);
        }
        acc *= 0.125f;
        sc[s] = acc;
        lmax = fmaxf(lmax, acc);
    }
    red[tid] = lmax; __syncthreads();
    for (int off = 128; off > 0; off >>= 1) { if (tid < off) red[tid] = fmaxf(red[tid], red[tid + off]); __syncthreads(); }
    const float m = red[0]; __syncthreads();
    float lsum = 0.f;
    for (int s = tid; s <= t; s += 256) { float e = __expf(sc[s] - m); sc[s] = e; lsum += e; }
    red[tid] = lsum; __syncthreads();
    for (int off = 128; off > 0; off >>= 1) { if (tid < off) red[tid] += red[tid + off]; __syncthreads(); }
    const float inv = 1.0f / red[0]; __syncthreads();
    const int c = tid & 63, g = tid >> 6;
    float acc = 0.f;
    for (int s = g; s <= t; s += 4) {
        float p = sc[s];
        float vv = qkv[(b * TT + s) * 192 + 128 + c];
        float ev = embv[(t - s) * CC + c];
        acc += p * (vv + ev);
    }
    yred[g][c] = acc * inv;
    __syncthreads();
    if (tid < CC) qs[tid] = yred[0][tid] + yred[1][tid] + yred[2][tid] + yred[3][tid];
    __syncthreads();
    if (tid < CC) {
        const float* w = Wproj + tid * CC;
        float o = bproj[tid];
        #pragma unroll
        for (int cc2 = 0; cc2 < CC; cc2 += 4) {
            float4 wq = *(const float4*)(w + cc2);
            float4 yq = *(const float4*)(qs + cc2);
            o += wq.x * yq.x + wq.y * yq.y + wq.z * yq.z + wq.w * yq.w;
        }
        out[bt * CC + tid] = o;
    }
}

extern "C" void kernel_launch(void* const* d_in, const int* in_sizes, int n_in,
                              void* d_out, int out_size, void* d_ws, size_t ws_size,
                              hipStream_t stream) {
    const float* x     = (const float*)d_in[0];
    const float* Wqkv  = (const float*)d_in[1];
    const float* bqkv  = (const float*)d_in[2];
    const float* embk  = (const float*)d_in[3];
    const float* embv  = (const float*)d_in[4];
    const float* Wproj = (const float*)d_in[5];
    const float* bproj = (const float*)d_in[6];
    float* out = (float*)d_out;

    if (ws_size < (WS_NEED > (size_t)BB * TT * 192 * 4 ? WS_NEED : (size_t)BB * TT * 192 * 4)) {
        float* qkv = (float*)d_ws;
        qkv_kernel<<<BB * TT, 192, 0, stream>>>(x, Wqkv, bqkv, qkv);
        attn_kernel<<<BB * TT, 256, 0, stream>>>(qkv, embk, embv, Wproj, bproj, out);
        return;
    }

    char* ws = (char*)d_ws;
    u16* x_bf       = (u16*)(ws + OFF_XBF);
    u16* q_bf       = (u16*)(ws + OFF_QBF);
    u16* k_bf       = (u16*)(ws + OFF_KBF);
    u16* vT_bf      = (u16*)(ws + OFF_VT);
    u16* embk_pad   = (u16*)(ws + OFF_EKP);
    u16* embvT_pad  = (u16*)(ws + OFF_EVT);
    u16* Wqkv_bf    = (u16*)(ws + OFF_WQKV);
    u16* Wproj_bf   = (u16*)(ws + OFF_WPROJ);

    prep_kernel<<<512, 256, 0, stream>>>(x, Wqkv, embk, embv, Wproj,
                                         x_bf, Wqkv_bf, embk_pad, embvT_pad, Wproj_bf);
    qkv_mfma_kernel<<<dim3(512, 12), 64, 0, stream>>>(x_bf, Wqkv_bf, bqkv, q_bf, k_bf, vT_bf);
    fused_attn_kernel<<<dim3(64, 8), 256, 0, stream>>>(q_bf, k_bf, vT_bf, embk_pad, embvT_pad,
                                                       Wproj_bf, bproj, out);
}